// Round 1
// 1322.587 us; speedup vs baseline: 1.0055x; 1.0055x over previous
//
#include <hip/hip_runtime.h>
#include <math.h>

// B=1024, S=512, H=512, D=2048
// risk = clip(0.25*(re/ln8) - 0.2*(1-mc) + 0.2*sigmoid(mm-2)
//             + 0.2*mean_s sigmoid(hs[b,s,:]·pw + pb)
//             + 0.15*sigmoid(1/(||rr[b]||+1e-8) - 1), 0, 1)
//
// Structure: 1 block per b, 4 waves. Each wave: 4 groups of 16 lanes,
// each group owns one token per iteration (token = wave*4 + group + 16*it).
// 16-lane-per-token => the cross-lane reduce is 4 shfl_xor that reduce ALL
// four tokens simultaneously (1 DS op per token vs 6 in the old wave-per-token
// scheme). Row loads are double-buffered: next iteration's 8 float4/lane are
// issued before the current reduce chain, keeping ~8KB/wave in flight.

#define S_TOK 512
#define H_DIM 512
#define D_DIM 2048
#define H4    128   // H_DIM/4 float4 per row

__device__ __forceinline__ float sigmoidf_fast(float x) {
    return 1.0f / (1.0f + __expf(-x));
}
__device__ __forceinline__ float dot4(float4 a, float4 b) {
    return a.x * b.x + a.y * b.y + a.z * b.z + a.w * b.w;
}

__global__ __launch_bounds__(256, 4) void halluc_kernel(
    const float* __restrict__ routing_entropy,
    const float* __restrict__ moe_confidence,
    const float* __restrict__ memory_mismatch,
    const float* __restrict__ hidden_states,
    const float* __restrict__ routing_repr,
    const float* __restrict__ probe_w,
    const float* __restrict__ probe_b,
    float* __restrict__ out)
{
    const int b    = blockIdx.x;
    const int tid  = threadIdx.x;
    const int lane = tid & 63;
    const int wave = tid >> 6;   // 0..3
    const int u    = lane & 15;  // sublane within the 16-lane group
    // group g = lane >> 4 (0..3)

    // ---- probe weights register-resident: lane's slice is w4[u + 16c], c=0..7
    const float4* pw4 = (const float4*)probe_w;
    float4 w[8];
    #pragma unroll
    for (int c = 0; c < 8; ++c) w[c] = pw4[u + 16 * c];
    const float pb = probe_b[0];

    const float4* hs4 = (const float4*)(hidden_states + (size_t)b * S_TOK * H_DIM);
    const int t0 = wave * 4 + (lane >> 4);   // token(it) = t0 + 16*it, it in [0,32)

    // ---- preload first row (split in two halves for scheduling slack)
    float4 bufA[4], bufB[4];
    {
        const float4* row = hs4 + (size_t)t0 * H4;
        #pragma unroll
        for (int c = 0; c < 4; ++c) bufA[c] = row[u + 16 * c];
        #pragma unroll
        for (int c = 0; c < 4; ++c) bufB[c] = row[u + 16 * c + 64];
    }

    float sem = 0.0f;

    auto consume = [&](const float4* A, const float4* Bv) {
        float d0 = dot4(A[0],  w[0]) + dot4(A[2],  w[2]);
        float d1 = dot4(A[1],  w[1]) + dot4(A[3],  w[3]);
        float d2 = dot4(Bv[0], w[4]) + dot4(Bv[2], w[6]);
        float d3 = dot4(Bv[1], w[5]) + dot4(Bv[3], w[7]);
        float d  = (d0 + d1) + (d2 + d3);
        // reduce within each 16-lane group: every lane ends with its token's dot
        d += __shfl_xor(d, 8, 64);
        d += __shfl_xor(d, 4, 64);
        d += __shfl_xor(d, 2, 64);
        d += __shfl_xor(d, 1, 64);
        sem += sigmoidf_fast(d + pb);
    };

    #pragma unroll 2
    for (int it = 0; it < 31; ++it) {
        // prefetch next iteration's row BEFORE consuming the current one
        const float4* nrow = hs4 + (size_t)(t0 + 16 * (it + 1)) * H4;
        float4 nA[4], nB[4];
        #pragma unroll
        for (int c = 0; c < 4; ++c) nA[c] = nrow[u + 16 * c];
        #pragma unroll
        for (int c = 0; c < 4; ++c) nB[c] = nrow[u + 16 * c + 64];

        consume(bufA, bufB);

        #pragma unroll
        for (int c = 0; c < 4; ++c) { bufA[c] = nA[c]; bufB[c] = nB[c]; }
    }
    consume(bufA, bufB);   // last iteration, no prefetch

    // combine the 4 group-sums -> every lane holds the wave total
    sem += __shfl_xor(sem, 16, 64);
    sem += __shfl_xor(sem, 32, 64);

    // ---- eigen score: sum of squares of routing_repr[b, 0:2048] (8KB/block)
    const float4* rr4 = (const float4*)(routing_repr + (size_t)b * D_DIM);
    const float4 r0 = rr4[tid];
    const float4 r1 = rr4[tid + 256];
    float sq = r0.x * r0.x + r0.y * r0.y + r0.z * r0.z + r0.w * r0.w
             + r1.x * r1.x + r1.y * r1.y + r1.z * r1.z + r1.w * r1.w;
    #pragma unroll
    for (int m = 32; m > 0; m >>= 1) sq += __shfl_xor(sq, m, 64);

    __shared__ float s_sem[4];
    __shared__ float s_sq[4];
    if (lane == 0) { s_sem[wave] = sem; s_sq[wave] = sq; }
    __syncthreads();

    if (tid == 0) {
        const float sem_mean = (s_sem[0] + s_sem[1] + s_sem[2] + s_sem[3]) * (1.0f / S_TOK);
        const float sv       = sqrtf(s_sq[0] + s_sq[1] + s_sq[2] + s_sq[3]);
        const float neig     = sigmoidf_fast(1.0f / (sv + 1e-8f) - 1.0f);

        const float ne = routing_entropy[b] * 0.48089834696298783f;  // 1/ln(8)
        const float ic = 1.0f - moe_confidence[b];
        const float nm = sigmoidf_fast(memory_mismatch[b] - 2.0f);

        float risk = 0.25f * ne - 0.2f * ic + 0.2f * nm
                   + 0.2f * sem_mean + 0.15f * neig;
        risk = fminf(fmaxf(risk, 0.0f), 1.0f);
        out[b] = risk;
    }
}

extern "C" void kernel_launch(void* const* d_in, const int* in_sizes, int n_in,
                              void* d_out, int out_size, void* d_ws, size_t ws_size,
                              hipStream_t stream) {
    const float* routing_entropy = (const float*)d_in[0];
    const float* moe_confidence  = (const float*)d_in[1];
    const float* memory_mismatch = (const float*)d_in[2];
    // d_in[3] = memory_loss (unused by reference)
    const float* hidden_states   = (const float*)d_in[4];
    const float* routing_repr    = (const float*)d_in[5];
    const float* probe_w         = (const float*)d_in[6];
    const float* probe_b         = (const float*)d_in[7];
    float* out = (float*)d_out;

    const int B = in_sizes[0];  // 1024

    halluc_kernel<<<B, 256, 0, stream>>>(
        routing_entropy, moe_confidence, memory_mismatch,
        hidden_states, routing_repr, probe_w, probe_b, out);
}